// Round 3
// baseline (1829.555 us; speedup 1.0000x reference)
//
#include <hip/hip_runtime.h>
#include <math.h>

#define NB 8
#define NN 2048
#define NM 2048
#define NITERS 50

static constexpr float F_EPS  = 0.005f;
static constexpr float LOG2E  = 1.4426950408889634f;
static constexpr float KK     = LOG2E / F_EPS;      // 288.539008...
static constexpr float TWOK   = 2.0f * KK;
static constexpr float NEG_LOG2N = -11.0f;          // -log2(2048)

__device__ __forceinline__ float fexp2(float x) { return __builtin_amdgcn_exp2f(x); }
__device__ __forceinline__ float flog2(float x) { return __builtin_amdgcn_logf(x); }

// ---------------------------------------------------------------------------
// Pack: P[i] = (v0, v1, v2, K*(dual - |v|^2)) with dual = 0.
// ---------------------------------------------------------------------------
__global__ void pack_init(const float* __restrict__ V, float4* __restrict__ Pout, int total)
{
    int i = blockIdx.x * blockDim.x + threadIdx.x;
    if (i < total) {
        float v0 = V[3*i], v1 = V[3*i+1], v2 = V[3*i+2];
        float s  = fmaf(v0, v0, fmaf(v1, v1, v2*v2));
        Pout[i]  = make_float4(v0, v1, v2, -KK * s);
    }
}

// ---------------------------------------------------------------------------
// One Sinkhorn half-sweep, full-occupancy decomposition:
//   wg = 512 thr (8 waves), covers 16 rows x all 2048 m.
//   lane&15 = row-in-group, lane>>4 = m-quarter; chunk c = wave*4 + quarter
//   covers m in [c*64, c*64+64).  32 chunks x 16 rows partials -> LDS combine.
//
// LSE computed on z' = A_m + 2K*(x.y)  (B0 = K|x|^2 folded out; it cancels:
//   Aout = K*(dual_new - |x|^2) = -11 - lse2(z')).
// ---------------------------------------------------------------------------
__global__ __launch_bounds__(512, 8) void sink_update(
    const float4* __restrict__ Pin,   // [B][M] packed opposite side
    const float*  __restrict__ Vraw,  // [B][N][3] raw points of side being updated
    float4*       __restrict__ Pout)  // [B][N] packed output
{
    __shared__ float2 part[32][16];
    const int tid  = threadIdx.x;
    const int lane = tid & 63;
    const int wave = tid >> 6;
    const int r    = lane & 15;                 // row within 16-row group
    const int q    = lane >> 4;                 // m-quarter within wave
    const int c    = wave * 4 + q;              // chunk id 0..31 (64 m's each)
    const int wgs_per_b = NN / 16;              // 128
    const int b    = blockIdx.x / wgs_per_b;
    const int rowbase = (blockIdx.x % wgs_per_b) * 16;

    const float* vp = Vraw + ((size_t)(b * NN + rowbase + r)) * 3;
    const float x0 = vp[0], x1 = vp[1], x2 = vp[2];
    const float xs0 = TWOK * x0, xs1 = TWOK * x1, xs2 = TWOK * x2;

    const float4* __restrict__ pp = Pin + b * NM + c * 64;

    float run_m = -1e30f, run_s = 0.f;
    for (int i = 0; i < 64; i += 4) {
        float z0, z1, z2, z3;
        {
            const float4 p = pp[i + 0];
            z0 = fmaf(xs0, p.x, fmaf(xs1, p.y, fmaf(xs2, p.z, p.w)));
        }
        {
            const float4 p = pp[i + 1];
            z1 = fmaf(xs0, p.x, fmaf(xs1, p.y, fmaf(xs2, p.z, p.w)));
        }
        {
            const float4 p = pp[i + 2];
            z2 = fmaf(xs0, p.x, fmaf(xs1, p.y, fmaf(xs2, p.z, p.w)));
        }
        {
            const float4 p = pp[i + 3];
            z3 = fmaf(xs0, p.x, fmaf(xs1, p.y, fmaf(xs2, p.z, p.w)));
        }
        const float cmax = fmaxf(fmaxf(z0, z1), fmaxf(z2, z3));
        const float nm   = fmaxf(run_m, cmax);
        const float s01  = fexp2(z0 - nm) + fexp2(z1 - nm);
        const float s23  = fexp2(z2 - nm) + fexp2(z3 - nm);
        run_s = fmaf(run_s, fexp2(run_m - nm), s01 + s23);
        run_m = nm;
    }

    part[c][r] = make_float2(run_m, run_s);
    __syncthreads();

    if (tid < 16) {   // lane tid of wave 0 holds row rowbase+tid's x regs
        float gm = -1e30f;
        #pragma unroll
        for (int k = 0; k < 32; ++k) gm = fmaxf(gm, part[k][tid].x);
        float s = 0.f;
        #pragma unroll
        for (int k = 0; k < 32; ++k) s = fmaf(part[k][tid].y, fexp2(part[k][tid].x - gm), s);
        const float lse2 = gm + flog2(s);       // log2 sum of exp2(z')
        Pout[b * NN + rowbase + tid] = make_float4(x0, x1, x2, NEG_LOG2N - lse2);
    }
}

// ---------------------------------------------------------------------------
// Final loss: out = (1/B) * sum_{b,n,m} P*C,  P = exp2(Af + Ag + 2K*dot),
// C = max(|x|^2+|y|^2-2dot, 0).  Same decomposition; global sum.
// ---------------------------------------------------------------------------
__global__ __launch_bounds__(512, 8) void final_loss(
    const float4* __restrict__ Px, const float4* __restrict__ Py,
    float* __restrict__ out)
{
    __shared__ float wsum[8];
    const int tid  = threadIdx.x;
    const int lane = tid & 63;
    const int wave = tid >> 6;
    const int r    = lane & 15;
    const int q    = lane >> 4;
    const int c    = wave * 4 + q;
    const int wgs_per_b = NN / 16;
    const int b    = blockIdx.x / wgs_per_b;
    const int rowbase = (blockIdx.x % wgs_per_b) * 16;

    const float4 xp = Px[b * NN + rowbase + r];
    const float x0 = xp.x, x1 = xp.y, x2 = xp.z, Af = xp.w;
    const float xsq = fmaf(x0, x0, fmaf(x1, x1, x2 * x2));

    const float4* __restrict__ pp = Py + b * NM + c * 64;

    float acc = 0.f;
    #pragma unroll 4
    for (int i = 0; i < 64; ++i) {
        const float4 p = pp[i];
        const float dot = fmaf(x0, p.x, fmaf(x1, p.y, x2 * p.z));
        const float ysq = fmaf(p.x, p.x, fmaf(p.y, p.y, p.z * p.z));
        float cc = fmaf(-2.f, dot, xsq + ysq);
        cc = fmaxf(cc, 0.f);
        const float zp = fmaf(TWOK, dot, Af + p.w);
        acc = fmaf(fexp2(zp), cc, acc);
    }
    #pragma unroll
    for (int o = 32; o > 0; o >>= 1) acc += __shfl_xor(acc, o);
    if (lane == 0) wsum[wave] = acc;
    __syncthreads();
    if (tid == 0) {
        float t = 0.f;
        #pragma unroll
        for (int w = 0; w < 8; ++w) t += wsum[w];
        atomicAdd(out, t * (1.0f / NB));
    }
}

// ---------------------------------------------------------------------------
extern "C" void kernel_launch(void* const* d_in, const int* in_sizes, int n_in,
                              void* d_out, int out_size, void* d_ws, size_t ws_size,
                              hipStream_t stream)
{
    const float* x = (const float*)d_in[0];
    const float* y = (const float*)d_in[1];
    float4* Px = (float4*)d_ws;            // [B][N] packed x-side
    float4* Py = Px + NB * NN;             // [B][M] packed y-side

    pack_init<<<(NB * NM + 255) / 256, 256, 0, stream>>>(y, Py, NB * NM);

    for (int it = 0; it < NITERS; ++it) {
        sink_update<<<NB * NN / 16, 512, 0, stream>>>(Py, x, Px);  // f-update
        sink_update<<<NB * NM / 16, 512, 0, stream>>>(Px, y, Py);  // g-update
    }

    hipMemsetAsync(d_out, 0, sizeof(float), stream);
    final_loss<<<NB * NN / 16, 512, 0, stream>>>(Px, Py, (float*)d_out);
}

// Round 4
// 1147.492 us; speedup vs baseline: 1.5944x; 1.5944x over previous
//
#include <hip/hip_runtime.h>
#include <math.h>

#define NB 8
#define NN 2048
#define NM 2048
#define NITERS 50

static constexpr float F_EPS  = 0.005f;
static constexpr float LOG2E  = 1.4426950408889634f;
static constexpr float KK     = LOG2E / F_EPS;      // 288.539...
static constexpr float TWOK   = 2.0f * KK;
static constexpr float NEG_LOG2N = -11.0f;          // -log2(2048)

__device__ __forceinline__ float fexp2(float x) { return __builtin_amdgcn_exp2f(x); }
__device__ __forceinline__ float flog2(float x) { return __builtin_amdgcn_logf(x); }

// ---------------------------------------------------------------------------
// Pack: P[i] = (v0, v1, v2, K*(dual - |v|^2)) with dual = 0.
// ---------------------------------------------------------------------------
__global__ void pack_init(const float* __restrict__ V, float4* __restrict__ Pout, int total)
{
    int i = blockIdx.x * blockDim.x + threadIdx.x;
    if (i < total) {
        float v0 = V[3*i], v1 = V[3*i+1], v2 = V[3*i+2];
        float s  = fmaf(v0, v0, fmaf(v1, v1, v2*v2));
        Pout[i]  = make_float4(v0, v1, v2, -KK * s);
    }
}

// ---------------------------------------------------------------------------
// Sinkhorn half-sweep, row-blocked (8 rows per lane -> 8x less L2 traffic).
//   wg = 256 thr (4 waves). Wave w owns rows [rowbase+8w, rowbase+8w+8).
//   Each lane sweeps m = lane + 64*i, i=0..31 (coalesced 1KB/wave-load),
//   reusing each loaded float4 for all 8 rows. Streaming chunked LSE
//   (4 m's per rescale). Two-stage LDS combine of 64 lane-partials/row.
// ---------------------------------------------------------------------------
__global__ __launch_bounds__(256, 4) void sink_update(
    const float4* __restrict__ Pin,   // [B][M] packed opposite side
    const float*  __restrict__ Vraw,  // [B][N][3] raw points of side being updated
    float4*       __restrict__ Pout)  // [B][N] packed output
{
    __shared__ float2 part [32][65];  // [row][lane] padded (bank spread)
    __shared__ float2 part2[32][9];   // [row][seg]
    const int tid  = threadIdx.x;
    const int lane = tid & 63;
    const int wave = tid >> 6;                  // 0..3
    const int wgs_per_b = NN / 32;              // 64
    const int b       = blockIdx.x / wgs_per_b;
    const int rowbase = (blockIdx.x % wgs_per_b) * 32;

    // this wave's 8 rows: scaled coords in registers
    float xs0[8], xs1[8], xs2[8];
    {
        const float* vb = Vraw + ((size_t)(b * NN + rowbase + wave * 8)) * 3;
        #pragma unroll
        for (int r = 0; r < 8; ++r) {
            xs0[r] = TWOK * vb[r*3+0];
            xs1[r] = TWOK * vb[r*3+1];
            xs2[r] = TWOK * vb[r*3+2];
        }
    }

    const float4* __restrict__ pp = Pin + b * NM + lane;

    float rm[8], rs[8];
    #pragma unroll
    for (int r = 0; r < 8; ++r) { rm[r] = -1e30f; rs[r] = 0.f; }

    for (int ib = 0; ib < 8; ++ib) {
        const float4 p0 = pp[(ib*4 + 0) * 64];
        const float4 p1 = pp[(ib*4 + 1) * 64];
        const float4 p2 = pp[(ib*4 + 2) * 64];
        const float4 p3 = pp[(ib*4 + 3) * 64];
        #pragma unroll
        for (int r = 0; r < 8; ++r) {
            const float z0 = fmaf(xs0[r], p0.x, fmaf(xs1[r], p0.y, fmaf(xs2[r], p0.z, p0.w)));
            const float z1 = fmaf(xs0[r], p1.x, fmaf(xs1[r], p1.y, fmaf(xs2[r], p1.z, p1.w)));
            const float z2 = fmaf(xs0[r], p2.x, fmaf(xs1[r], p2.y, fmaf(xs2[r], p2.z, p2.w)));
            const float z3 = fmaf(xs0[r], p3.x, fmaf(xs1[r], p3.y, fmaf(xs2[r], p3.z, p3.w)));
            const float cm = fmaxf(fmaxf(z0, z1), fmaxf(z2, z3));
            const float nm = fmaxf(rm[r], cm);
            const float s  = (fexp2(z0 - nm) + fexp2(z1 - nm))
                           + (fexp2(z2 - nm) + fexp2(z3 - nm));
            rs[r] = fmaf(rs[r], fexp2(rm[r] - nm), s);
            rm[r] = nm;
        }
    }

    #pragma unroll
    for (int r = 0; r < 8; ++r) part[wave*8 + r][lane] = make_float2(rm[r], rs[r]);
    __syncthreads();

    // stage 2: 256 threads, each folds 8 lane-partials of one row
    {
        const int row = tid >> 3, seg = tid & 7;
        float m8 = -1e30f;
        float2 v[8];
        #pragma unroll
        for (int k = 0; k < 8; ++k) { v[k] = part[row][seg*8 + k]; m8 = fmaxf(m8, v[k].x); }
        float s8 = 0.f;
        #pragma unroll
        for (int k = 0; k < 8; ++k) s8 = fmaf(v[k].y, fexp2(v[k].x - m8), s8);
        part2[row][seg] = make_float2(m8, s8);
    }
    __syncthreads();

    // stage 3: 32 threads, final fold + write packed output
    if (tid < 32) {
        float gm = -1e30f;
        float2 v[8];
        #pragma unroll
        for (int k = 0; k < 8; ++k) { v[k] = part2[tid][k]; gm = fmaxf(gm, v[k].x); }
        float s = 0.f;
        #pragma unroll
        for (int k = 0; k < 8; ++k) s = fmaf(v[k].y, fexp2(v[k].x - gm), s);
        const float lse2 = gm + flog2(s);
        const int n0 = rowbase + tid;
        const float* vp = Vraw + ((size_t)(b * NN + n0)) * 3;
        Pout[b * NN + n0] = make_float4(vp[0], vp[1], vp[2], NEG_LOG2N - lse2);
    }
}

// ---------------------------------------------------------------------------
// Final loss, same row-blocked structure.
// out = (1/B) * sum P*C, P = exp2(Af + Ag + 2K*dot), C = max(|x|^2+|y|^2-2dot,0)
// ---------------------------------------------------------------------------
__global__ __launch_bounds__(256, 4) void final_loss(
    const float4* __restrict__ Px, const float4* __restrict__ Py,
    float* __restrict__ out)
{
    __shared__ float wsum[4];
    const int tid  = threadIdx.x;
    const int lane = tid & 63;
    const int wave = tid >> 6;
    const int wgs_per_b = NN / 32;
    const int b       = blockIdx.x / wgs_per_b;
    const int rowbase = (blockIdx.x % wgs_per_b) * 32;

    float xr0[8], xr1[8], xr2[8], Af[8], xq[8];
    {
        const float4* xb = Px + b * NN + rowbase + wave * 8;
        #pragma unroll
        for (int r = 0; r < 8; ++r) {
            const float4 xp = xb[r];
            xr0[r] = xp.x; xr1[r] = xp.y; xr2[r] = xp.z; Af[r] = xp.w;
            xq[r]  = fmaf(xp.x, xp.x, fmaf(xp.y, xp.y, xp.z * xp.z));
        }
    }

    const float4* __restrict__ pp = Py + b * NM + lane;

    float acc = 0.f;
    for (int i = 0; i < 32; ++i) {
        const float4 p = pp[i * 64];
        const float ysq = fmaf(p.x, p.x, fmaf(p.y, p.y, p.z * p.z));
        #pragma unroll
        for (int r = 0; r < 8; ++r) {
            const float dot = fmaf(xr0[r], p.x, fmaf(xr1[r], p.y, xr2[r] * p.z));
            const float cc  = fmaxf(fmaf(-2.f, dot, xq[r] + ysq), 0.f);
            const float zp  = fmaf(TWOK, dot, Af[r] + p.w);
            acc = fmaf(fexp2(zp), cc, acc);
        }
    }
    #pragma unroll
    for (int o = 32; o > 0; o >>= 1) acc += __shfl_xor(acc, o);
    if (lane == 0) wsum[wave] = acc;
    __syncthreads();
    if (tid == 0) {
        atomicAdd(out, (wsum[0] + wsum[1] + wsum[2] + wsum[3]) * (1.0f / NB));
    }
}

// ---------------------------------------------------------------------------
extern "C" void kernel_launch(void* const* d_in, const int* in_sizes, int n_in,
                              void* d_out, int out_size, void* d_ws, size_t ws_size,
                              hipStream_t stream)
{
    const float* x = (const float*)d_in[0];
    const float* y = (const float*)d_in[1];
    float4* Px = (float4*)d_ws;            // [B][N] packed x-side
    float4* Py = Px + NB * NN;             // [B][M] packed y-side

    pack_init<<<(NB * NM + 255) / 256, 256, 0, stream>>>(y, Py, NB * NM);

    for (int it = 0; it < NITERS; ++it) {
        sink_update<<<NB * NN / 32, 256, 0, stream>>>(Py, x, Px);  // f-update
        sink_update<<<NB * NM / 32, 256, 0, stream>>>(Px, y, Py);  // g-update
    }

    hipMemsetAsync(d_out, 0, sizeof(float), stream);
    final_loss<<<NB * NN / 32, 256, 0, stream>>>(Px, Py, (float*)d_out);
}